// Round 10
// baseline (623.511 us; speedup 1.0000x reference)
//
#include <hip/hip_runtime.h>
#include <hip/hip_bf16.h>

#define IN_F   256
#define HID    64
#define HEADS  8
#define OUTC   40
#define ALPHA_SLOPE 0.2f
#define F1     (HEADS*HID)   // 512

typedef short bf16x8 __attribute__((ext_vector_type(8)));
typedef float f32x4  __attribute__((ext_vector_type(4)));

// ---------------- CSR build ----------------

__global__ void hist_kernel(const int* __restrict__ col, int* __restrict__ cnt,
                            int E, int N) {
    int k = blockIdx.x * 256 + threadIdx.x;
    int tot = E + N;
    if (k >= tot) return;
    int c = (k < E) ? col[k] : (k - E);
    atomicAdd(&cnt[c], 1);
}

__global__ __launch_bounds__(1024) void scan1_kernel(
    const int* __restrict__ cnt, int* __restrict__ excl,
    int* __restrict__ bsum, int N) {
    __shared__ int wsum[16];
    int tid = threadIdx.x;
    int i = blockIdx.x * 1024 + tid;
    int lane = tid & 63, wid = tid >> 6;
    int v = (i < N) ? cnt[i] : 0;
    int incl = v;
    #pragma unroll
    for (int off = 1; off < 64; off <<= 1) {
        int t = __shfl_up(incl, off);
        if (lane >= off) incl += t;
    }
    if (lane == 63) wsum[wid] = incl;
    __syncthreads();
    if (wid == 0) {
        int w = (lane < 16) ? wsum[lane] : 0;
        #pragma unroll
        for (int off = 1; off < 16; off <<= 1) {
            int t = __shfl_up(w, off);
            if (lane >= off) w += t;
        }
        if (lane < 16) wsum[lane] = w;
    }
    __syncthreads();
    int woff = (wid > 0) ? wsum[wid - 1] : 0;
    int e = woff + incl - v;
    if (i < N) excl[i] = e;
    if (tid == 1023) bsum[blockIdx.x] = woff + incl;
}

__global__ void scan2_kernel(const int* __restrict__ bsum, int* __restrict__ boff,
                             int* __restrict__ indptrN, int nb) {
    int lane = threadIdx.x;
    int v = (lane < nb) ? bsum[lane] : 0;
    int incl = v;
    #pragma unroll
    for (int off = 1; off < 64; off <<= 1) {
        int t = __shfl_up(incl, off);
        if (lane >= off) incl += t;
    }
    if (lane < nb) boff[lane] = incl - v;
    if (lane == 63) *indptrN = incl;
}

__global__ void scan3_kernel(const int* __restrict__ boff, int* __restrict__ indptr,
                             int* __restrict__ fill, int N) {
    int i = blockIdx.x * 256 + threadIdx.x;
    if (i >= N) return;
    int e = indptr[i] + boff[i >> 10];
    indptr[i] = e;
    fill[i] = e;
}

__global__ void scatter_kernel(const int* __restrict__ row, const int* __restrict__ col,
                               int* __restrict__ fill, int* __restrict__ csr,
                               int E, int N) {
    int k = blockIdx.x * 256 + threadIdx.x;
    int tot = E + N;
    if (k >= tot) return;
    int c = (k < E) ? col[k] : (k - E);
    int r = (k < E) ? row[k] : (k - E);
    int pos = atomicAdd(&fill[c], 1);
    csr[pos] = r;
}

// ---------------- fused prep: cvt x, transpose W0/W1, pack Wout ----------------

__global__ void prep_all_kernel(const float* __restrict__ x, __hip_bfloat16* __restrict__ xb,
                                long nx,
                                const float* __restrict__ W0, __hip_bfloat16* __restrict__ Wt0,
                                const float* __restrict__ W1, __hip_bfloat16* __restrict__ Wt1,
                                const float* __restrict__ Wout, __hip_bfloat16* __restrict__ WtO,
                                int nbA, int nbB, int nbC) {
    int b = blockIdx.x;
    if (b < nbA) {
        long i = ((long)b * 256 + threadIdx.x) * 4;
        if (i + 3 >= nx) {
            for (long j = i; j < nx; j++) xb[j] = __float2bfloat16(x[j]);
            return;
        }
        float4 v = *(const float4*)(x + i);
        xb[i + 0] = __float2bfloat16(v.x);
        xb[i + 1] = __float2bfloat16(v.y);
        xb[i + 2] = __float2bfloat16(v.z);
        xb[i + 3] = __float2bfloat16(v.w);
    } else if (b < nbA + nbB) {
        long i = (long)(b - nbA) * 256 + threadIdx.x;
        const int K = IN_F;
        if (i >= (long)HEADS * K * 64) return;
        int n = i & 63;
        long rest = i >> 6;
        int k = (int)(rest % K);
        int h = (int)(rest / K);
        Wt0[((long)h * 64 + n) * K + k] = __float2bfloat16(W0[i]);
    } else if (b < nbA + nbB + nbC) {
        long i = (long)(b - nbA - nbB) * 256 + threadIdx.x;
        const int K = F1;
        if (i >= (long)HEADS * K * 64) return;
        int n = i & 63;
        long rest = i >> 6;
        int k = (int)(rest % K);
        int h = (int)(rest / K);
        Wt1[((long)h * 64 + n) * K + k] = __float2bfloat16(W1[i]);
    } else {
        int i = (b - nbA - nbB - nbC) * 256 + threadIdx.x;
        if (i >= 64 * 512) return;
        int k = i & 511;
        int n = i >> 9;
        WtO[i] = __float2bfloat16(n < OUTC ? Wout[(long)k * OUTC + n] : 0.f);
    }
}

// ---------------- dense 128x128 bf16 MFMA GEMM, BK=64 double-chunk ----------------
// Two 32-K chunks staged per barrier pair (halves barrier count) + register
// prefetch of the next 64-K block between barrier and MFMA. Epilogue fuses
// per-head attention scores from fp32 accumulators.

__global__ __launch_bounds__(256) void gemm128(
    const __hip_bfloat16* __restrict__ A, const __hip_bfloat16* __restrict__ Bt,
    __hip_bfloat16* __restrict__ Cb, const float* __restrict__ av,
    float* __restrict__ ssrc, float* __restrict__ sdst, int M, int K) {
    constexpr int LDA = 40;
    __shared__ __hip_bfloat16 As[2][128 * LDA];
    __shared__ __hip_bfloat16 Bs[2][128 * LDA];
    int tid = threadIdx.x;
    int m0 = blockIdx.x * 128;
    int n0 = blockIdx.y * 128;
    int lane = tid & 63, wave = tid >> 6;
    int wm = (wave & 1) * 64, wn = (wave >> 1) * 64;
    int fr = lane & 15, fq = lane >> 4;
    int srow = tid >> 1, scol = (tid & 1) * 16;
    int h = blockIdx.y * 2 + (wave >> 1);     // this wave's head

    const __hip_bfloat16* Arow = A + (long)min(m0 + srow, M - 1) * K;
    const __hip_bfloat16* Brow = Bt + (long)(n0 + srow) * K;

    f32x4 acc[4][4] = {};

    // preload first 64-K block (two 32-chunks)
    float4 a00 = *(const float4*)(Arow + scol);
    float4 a01 = *(const float4*)(Arow + scol + 8);
    float4 a10 = *(const float4*)(Arow + 32 + scol);
    float4 a11 = *(const float4*)(Arow + 32 + scol + 8);
    float4 b00 = *(const float4*)(Brow + scol);
    float4 b01 = *(const float4*)(Brow + scol + 8);
    float4 b10 = *(const float4*)(Brow + 32 + scol);
    float4 b11 = *(const float4*)(Brow + 32 + scol + 8);

    for (int k0 = 0; k0 < K; k0 += 64) {
        __syncthreads();
        *(float4*)(&As[0][srow * LDA + scol]) = a00;
        *(float4*)(&As[0][srow * LDA + scol + 8]) = a01;
        *(float4*)(&As[1][srow * LDA + scol]) = a10;
        *(float4*)(&As[1][srow * LDA + scol + 8]) = a11;
        *(float4*)(&Bs[0][srow * LDA + scol]) = b00;
        *(float4*)(&Bs[0][srow * LDA + scol + 8]) = b01;
        *(float4*)(&Bs[1][srow * LDA + scol]) = b10;
        *(float4*)(&Bs[1][srow * LDA + scol + 8]) = b11;
        __syncthreads();
        // prefetch next block (safe dummy address on last iter)
        int kn = (k0 + 64 < K) ? k0 + 64 : 0;
        a00 = *(const float4*)(Arow + kn + scol);
        a01 = *(const float4*)(Arow + kn + scol + 8);
        a10 = *(const float4*)(Arow + kn + 32 + scol);
        a11 = *(const float4*)(Arow + kn + 32 + scol + 8);
        b00 = *(const float4*)(Brow + kn + scol);
        b01 = *(const float4*)(Brow + kn + scol + 8);
        b10 = *(const float4*)(Brow + kn + 32 + scol);
        b11 = *(const float4*)(Brow + kn + 32 + scol + 8);
        #pragma unroll
        for (int c = 0; c < 2; c++) {
            bf16x8 af[4], bfr[4];
            #pragma unroll
            for (int mi = 0; mi < 4; mi++)
                af[mi] = *(const bf16x8*)(&As[c][(wm + mi * 16 + fr) * LDA + fq * 8]);
            #pragma unroll
            for (int ni = 0; ni < 4; ni++)
                bfr[ni] = *(const bf16x8*)(&Bs[c][(wn + ni * 16 + fr) * LDA + fq * 8]);
            #pragma unroll
            for (int mi = 0; mi < 4; mi++)
                #pragma unroll
                for (int ni = 0; ni < 4; ni++)
                    acc[mi][ni] = __builtin_amdgcn_mfma_f32_16x16x32_bf16(
                        af[mi], bfr[ni], acc[mi][ni], 0, 0, 0);
        }
    }

    // C write (bf16)
    #pragma unroll
    for (int mi = 0; mi < 4; mi++)
        #pragma unroll
        for (int ni = 0; ni < 4; ni++)
            #pragma unroll
            for (int rr = 0; rr < 4; rr++) {
                int m = m0 + wm + mi * 16 + fq * 4 + rr;
                int n = n0 + wn + ni * 16 + fr;
                if (m < M)
                    Cb[(long)m * F1 + n] = __float2bfloat16(acc[mi][ni][rr]);
            }

    // fused scores: s = C_tile . a  (per row, this head)
    const float* ah = av + h * 2 * HID;
    float a_src[4], a_dst[4];
    #pragma unroll
    for (int ni = 0; ni < 4; ni++) {
        a_src[ni] = ah[ni * 16 + fr];
        a_dst[ni] = ah[64 + ni * 16 + fr];
    }
    #pragma unroll
    for (int mi = 0; mi < 4; mi++)
        #pragma unroll
        for (int rr = 0; rr < 4; rr++) {
            float ps = 0.f, pd = 0.f;
            #pragma unroll
            for (int ni = 0; ni < 4; ni++) {
                ps += acc[mi][ni][rr] * a_src[ni];
                pd += acc[mi][ni][rr] * a_dst[ni];
            }
            #pragma unroll
            for (int o = 1; o < 16; o <<= 1) {
                ps += __shfl_xor(ps, o);
                pd += __shfl_xor(pd, o);
            }
            int m = m0 + wm + mi * 16 + fq * 4 + rr;
            if (fr == 0 && m < M) {
                ssrc[m * HEADS + h] = ps;
                sdst[m * HEADS + h] = pd;
            }
        }
}

// ---------------- out-layer GEMM (bf16 C [N,40]) + fused scores ----------------

__global__ __launch_bounds__(256) void gemm_out(
    const __hip_bfloat16* __restrict__ A, const __hip_bfloat16* __restrict__ Bt,
    __hip_bfloat16* __restrict__ Cb, const float* __restrict__ av,
    float* __restrict__ ssrc, float* __restrict__ sdst, int M, int K) {
    constexpr int LDA = 40;
    __shared__ __hip_bfloat16 As[128 * LDA];
    __shared__ __hip_bfloat16 Bs[64 * LDA];
    int tid = threadIdx.x;
    int m0 = blockIdx.x * 128;
    int lane = tid & 63, wave = tid >> 6;
    int wm = wave * 32;
    int arow = tid >> 2, acol = (tid & 3) * 8;
    int fr = lane & 15, fq = lane >> 4;

    const __hip_bfloat16* Apa = A + (long)min(m0 + arow, M - 1) * K + acol;
    const __hip_bfloat16* Apb = A + (long)min(m0 + 64 + arow, M - 1) * K + acol;
    const __hip_bfloat16* Bp  = Bt + (long)arow * K + acol;

    f32x4 acc[2][4] = {};

    float4 av1 = *(const float4*)(Apa);
    float4 av2 = *(const float4*)(Apb);
    float4 bv  = *(const float4*)(Bp);

    for (int k0 = 0; k0 < K; k0 += 32) {
        __syncthreads();
        *(float4*)(As + arow * LDA + acol) = av1;
        *(float4*)(As + (64 + arow) * LDA + acol) = av2;
        *(float4*)(Bs + arow * LDA + acol) = bv;
        __syncthreads();
        int kn = (k0 + 32 < K) ? k0 + 32 : 0;
        av1 = *(const float4*)(Apa + kn);
        av2 = *(const float4*)(Apb + kn);
        bv  = *(const float4*)(Bp + kn);
        bf16x8 a0 = *(const bf16x8*)(As + (wm + fr) * LDA + fq * 8);
        bf16x8 a1 = *(const bf16x8*)(As + (wm + 16 + fr) * LDA + fq * 8);
        #pragma unroll
        for (int ni = 0; ni < 4; ni++) {
            bf16x8 b = *(const bf16x8*)(Bs + (ni * 16 + fr) * LDA + fq * 8);
            acc[0][ni] = __builtin_amdgcn_mfma_f32_16x16x32_bf16(a0, b, acc[0][ni], 0, 0, 0);
            acc[1][ni] = __builtin_amdgcn_mfma_f32_16x16x32_bf16(a1, b, acc[1][ni], 0, 0, 0);
        }
    }

    #pragma unroll
    for (int mi = 0; mi < 2; mi++)
        #pragma unroll
        for (int ni = 0; ni < 4; ni++)
            #pragma unroll
            for (int rr = 0; rr < 4; rr++) {
                int m = m0 + wm + mi * 16 + fq * 4 + rr;
                int n = ni * 16 + fr;
                if (m < M && n < OUTC)
                    Cb[(long)m * OUTC + n] = __float2bfloat16(acc[mi][ni][rr]);
            }

    float a_src[4], a_dst[4];
    #pragma unroll
    for (int ni = 0; ni < 4; ni++) {
        int c = ni * 16 + fr;
        a_src[ni] = (c < OUTC) ? av[c] : 0.f;
        a_dst[ni] = (c < OUTC) ? av[OUTC + c] : 0.f;
    }
    #pragma unroll
    for (int mi = 0; mi < 2; mi++)
        #pragma unroll
        for (int rr = 0; rr < 4; rr++) {
            float ps = 0.f, pd = 0.f;
            #pragma unroll
            for (int ni = 0; ni < 4; ni++) {
                ps += acc[mi][ni][rr] * a_src[ni];
                pd += acc[mi][ni][rr] * a_dst[ni];
            }
            #pragma unroll
            for (int o = 1; o < 16; o <<= 1) {
                ps += __shfl_xor(ps, o);
                pd += __shfl_xor(pd, o);
            }
            int m = m0 + wm + mi * 16 + fq * 4 + rr;
            if (fr == 0 && m < M) {
                ssrc[m] = ps;
                sdst[m] = pd;
            }
        }
}

// ---------------- aggregation: one wave per node, ALL 8 heads ----------------

__global__ __launch_bounds__(256) void agg8_kernel(
    const __hip_bfloat16* __restrict__ Whb, const float* __restrict__ ssrc,
    const float* __restrict__ sdst, const int* __restrict__ csr,
    const int* __restrict__ indptr, __hip_bfloat16* __restrict__ H, int N) {
    int node = blockIdx.x * 4 + (threadIdx.x >> 6);
    if (node >= N) return;
    int lane = threadIdx.x & 63;
    int h = lane >> 3;
    int e8 = lane & 7;
    int base_h = lane & 56;
    int s = __builtin_amdgcn_readfirstlane(indptr[node]);
    int e = __builtin_amdgcn_readfirstlane(indptr[node + 1]);
    float sd = sdst[node * HEADS + h];
    const __hip_bfloat16* wl = Whb + lane * 8;

    float acc[8] = {};
    float m_run = -1e30f, d_run = 0.f;

    for (int jb = s; jb < e; jb += 8) {
        int cnt = min(8, e - jb);
        int src_i = 0;
        float x_i = -1e30f;
        if (e8 < cnt) {
            src_i = csr[jb + e8];
            float x = ssrc[src_i * HEADS + h] + sd;
            x_i = x > 0.f ? x : ALPHA_SLOPE * x;
        }
        float tm = x_i;
        tm = fmaxf(tm, __shfl_xor(tm, 1));
        tm = fmaxf(tm, __shfl_xor(tm, 2));
        tm = fmaxf(tm, __shfl_xor(tm, 4));
        float nm = fmaxf(m_run, tm);
        float scale = __expf(m_run - nm);
        #pragma unroll
        for (int k = 0; k < 8; k++) acc[k] *= scale;
        d_run *= scale;
        m_run = nm;
        float w_i = __expf(x_i - nm);
        float ts = w_i;
        ts += __shfl_xor(ts, 1);
        ts += __shfl_xor(ts, 2);
        ts += __shfl_xor(ts, 4);
        d_run += ts;

        if (cnt == 8) {
            uint4 d[8];
            #pragma unroll
            for (int u = 0; u < 8; u++) {
                int su = __shfl(src_i, u);
                d[u] = *(const uint4*)(wl + (long)su * F1);
            }
            #pragma unroll
            for (int u = 0; u < 8; u++) {
                float wj = __shfl(w_i, base_h + u);
                acc[0] += wj * __uint_as_float(d[u].x << 16);
                acc[1] += wj * __uint_as_float(d[u].x & 0xffff0000u);
                acc[2] += wj * __uint_as_float(d[u].y << 16);
                acc[3] += wj * __uint_as_float(d[u].y & 0xffff0000u);
                acc[4] += wj * __uint_as_float(d[u].z << 16);
                acc[5] += wj * __uint_as_float(d[u].z & 0xffff0000u);
                acc[6] += wj * __uint_as_float(d[u].w << 16);
                acc[7] += wj * __uint_as_float(d[u].w & 0xffff0000u);
            }
        } else {
            for (int u = 0; u < cnt; u++) {
                float wj = __shfl(w_i, base_h + u);
                int   su = __shfl(src_i, u);
                uint4 d = *(const uint4*)(wl + (long)su * F1);
                acc[0] += wj * __uint_as_float(d.x << 16);
                acc[1] += wj * __uint_as_float(d.x & 0xffff0000u);
                acc[2] += wj * __uint_as_float(d.y << 16);
                acc[3] += wj * __uint_as_float(d.y & 0xffff0000u);
                acc[4] += wj * __uint_as_float(d.z << 16);
                acc[5] += wj * __uint_as_float(d.z & 0xffff0000u);
                acc[6] += wj * __uint_as_float(d.w << 16);
                acc[7] += wj * __uint_as_float(d.w & 0xffff0000u);
            }
        }
    }

    float inv = 1.f / d_run;
    unsigned short us[8];
    #pragma unroll
    for (int k = 0; k < 8; k++) {
        float v = acc[k] * inv;
        v = v > 0.f ? v : (__expf(v) - 1.f);
        __hip_bfloat16 b = __float2bfloat16(v);
        __builtin_memcpy(&us[k], &b, 2);
    }
    uint4 ov;
    __builtin_memcpy(&ov, us, 16);
    *(uint4*)(H + (long)node * F1 + lane * 8) = ov;
}

// ---------------- out aggregation (bf16 gather, batched) + log_softmax --------

__global__ __launch_bounds__(256) void aggout_kernel(
    const __hip_bfloat16* __restrict__ Whb, const float* __restrict__ ssrc,
    const float* __restrict__ sdst, const int* __restrict__ csr,
    const int* __restrict__ indptr, float* __restrict__ out, int N) {
    int node = blockIdx.x * 4 + (threadIdx.x >> 6);
    if (node >= N) return;
    int lane = threadIdx.x & 63;
    int s = __builtin_amdgcn_readfirstlane(indptr[node]);
    int e = __builtin_amdgcn_readfirstlane(indptr[node + 1]);
    float sd = sdst[node];
    int lc = min(lane, OUTC - 1);
    const __hip_bfloat16* whb = Whb + lc;

    float m_run = -1e30f, d_run = 0.f, acc0 = 0.f, acc1 = 0.f;
    for (int t = s; t < e; t += 64) {
        int cnt = min(64, e - t);
        int src_i = node;
        float x_i = -1e30f;
        if (lane < cnt) {
            src_i = csr[t + lane];
            float x = ssrc[src_i] + sd;
            x_i = x > 0.f ? x : ALPHA_SLOPE * x;
        }
        float tm = x_i;
        #pragma unroll
        for (int o = 32; o; o >>= 1) tm = fmaxf(tm, __shfl_xor(tm, o));
        float nm = fmaxf(m_run, tm);
        float scale = __expf(m_run - nm);
        acc0 *= scale; acc1 *= scale; d_run *= scale;
        m_run = nm;
        float w_i = __expf(x_i - nm);
        float ts = w_i;
        #pragma unroll
        for (int o = 32; o; o >>= 1) ts += __shfl_xor(ts, o);
        d_run += ts;
        int cnt8 = (cnt + 7) & ~7;         // pad lanes: w=0, src=node (safe)
        for (int j = 0; j < cnt8; j += 8) {
            float dv[8], wj[8];
            #pragma unroll
            for (int u = 0; u < 8; u++) {
                int sj = __shfl(src_i, j + u);
                wj[u] = __shfl(w_i, j + u);
                dv[u] = __bfloat162float(whb[(long)sj * OUTC]);
            }
            #pragma unroll
            for (int u = 0; u < 8; u += 2) {
                acc0 += wj[u] * dv[u];
                acc1 += wj[u + 1] * dv[u + 1];
            }
        }
    }
    float g = (acc0 + acc1) / d_run;
    float v = g > 0.f ? g : (__expf(g) - 1.f);
    float vm = (lane < OUTC) ? v : -1e30f;
    #pragma unroll
    for (int o = 32; o; o >>= 1) vm = fmaxf(vm, __shfl_xor(vm, o));
    float ex = (lane < OUTC) ? __expf(v - vm) : 0.f;
    #pragma unroll
    for (int o = 32; o; o >>= 1) ex += __shfl_xor(ex, o);
    if (lane < OUTC) out[(long)node * OUTC + lane] = v - vm - logf(ex);
}

// ---------------- launch ----------------

extern "C" void kernel_launch(void* const* d_in, const int* in_sizes, int n_in,
                              void* d_out, int out_size, void* d_ws, size_t ws_size,
                              hipStream_t stream) {
    const float* x    = (const float*)d_in[0];
    const int*   ei   = (const int*)d_in[1];
    const float* W0   = (const float*)d_in[2];
    const float* a0   = (const float*)d_in[3];
    const float* W1   = (const float*)d_in[4];
    const float* a1   = (const float*)d_in[5];
    const float* Wout = (const float*)d_in[6];
    const float* aout = (const float*)d_in[7];
    float* out = (float*)d_out;

    const int N = in_sizes[0] / IN_F;
    const int E = in_sizes[1] / 2;
    const int Etot = E + N;
    const int* erow = ei;
    const int* ecol = ei + E;

    char* p = (char*)d_ws;
    auto carve = [&](size_t bytes) {
        void* r = (void*)p;
        p += (bytes + 255) & ~(size_t)255;
        return r;
    };
    __hip_bfloat16*  Whb  = (__hip_bfloat16*)carve((size_t)N * F1 * 2);
    __hip_bfloat16*  Hb   = (__hip_bfloat16*)carve((size_t)N * F1 * 2);
    __hip_bfloat16*  WhOb = (__hip_bfloat16*)carve((size_t)N * OUTC * 2);
    __hip_bfloat16*  xb   = (__hip_bfloat16*)carve((size_t)N * IN_F * 2);
    __hip_bfloat16*  Wt0  = (__hip_bfloat16*)carve((size_t)F1 * IN_F * 2);
    __hip_bfloat16*  Wt1  = (__hip_bfloat16*)carve((size_t)F1 * F1 * 2);
    __hip_bfloat16*  WtO  = (__hip_bfloat16*)carve((size_t)64 * F1 * 2);
    float*  ssrc   = (float*)carve((size_t)N * HEADS * 4);
    float*  sdst   = (float*)carve((size_t)N * HEADS * 4);
    int*    cnt    = (int*)carve((size_t)N * 4);
    int*    indptr = (int*)carve((size_t)(N + 1) * 4);
    int*    fill   = (int*)carve((size_t)N * 4);
    int*    csr    = (int*)carve((size_t)Etot * 4);
    int*    bsum   = (int*)carve(64 * 4);
    int*    boff   = (int*)carve(64 * 4);

    // CSR build
    hipMemsetAsync(cnt, 0, (size_t)N * 4, stream);
    int eb = (Etot + 255) / 256;
    int nb = (N + 1023) / 1024;   // <=64 required by scan2
    hist_kernel<<<eb, 256, 0, stream>>>(ecol, cnt, E, N);
    scan1_kernel<<<nb, 1024, 0, stream>>>(cnt, indptr, bsum, N);
    scan2_kernel<<<1, 64, 0, stream>>>(bsum, boff, indptr + N, nb);
    scan3_kernel<<<(N + 255) / 256, 256, 0, stream>>>(boff, indptr, fill, N);
    scatter_kernel<<<eb, 256, 0, stream>>>(erow, ecol, fill, csr, E, N);

    // fused prep
    long nx = (long)N * IN_F;
    int nbA = (int)((nx / 4 + 255) / 256);
    int nbB = (HEADS * IN_F * 64 + 255) / 256;
    int nbC = (HEADS * F1 * 64 + 255) / 256;
    int nbD = (64 * 512 + 255) / 256;
    prep_all_kernel<<<nbA + nbB + nbC + nbD, 256, 0, stream>>>(
        x, xb, nx, W0, Wt0, W1, Wt1, Wout, WtO, nbA, nbB, nbC);

    int mt128 = (N + 127) / 128;
    int wb1 = (N + 3) / 4;

    // Layer 0
    gemm128<<<dim3(mt128, 4), 256, 0, stream>>>(xb, Wt0, Whb, a0, ssrc, sdst, N, IN_F);
    agg8_kernel<<<wb1, 256, 0, stream>>>(Whb, ssrc, sdst, csr, indptr, Hb, N);

    // Layer 1
    gemm128<<<dim3(mt128, 4), 256, 0, stream>>>(Hb, Wt1, Whb, a1, ssrc, sdst, N, F1);
    agg8_kernel<<<wb1, 256, 0, stream>>>(Whb, ssrc, sdst, csr, indptr, Hb, N);

    // Out layer
    gemm_out<<<dim3(mt128, 1), 256, 0, stream>>>(Hb, WtO, WhOb, aout, ssrc, sdst, N, F1);
    aggout_kernel<<<wb1, 256, 0, stream>>>(WhOb, ssrc, sdst, csr, indptr, out, N);
}

// Round 11
// 615.307 us; speedup vs baseline: 1.0133x; 1.0133x over previous
//
#include <hip/hip_runtime.h>
#include <hip/hip_bf16.h>

#define IN_F   256
#define HID    64
#define HEADS  8
#define OUTC   40
#define ALPHA_SLOPE 0.2f
#define F1     (HEADS*HID)   // 512

typedef short bf16x8 __attribute__((ext_vector_type(8)));
typedef float f32x4  __attribute__((ext_vector_type(4)));

// ---------------- CSR build ----------------

__global__ void hist_kernel(const int* __restrict__ col, int* __restrict__ cnt,
                            int E, int N) {
    int k = blockIdx.x * 256 + threadIdx.x;
    int tot = E + N;
    if (k >= tot) return;
    int c = (k < E) ? col[k] : (k - E);
    atomicAdd(&cnt[c], 1);
}

__global__ __launch_bounds__(1024) void scan1_kernel(
    const int* __restrict__ cnt, int* __restrict__ excl,
    int* __restrict__ bsum, int N) {
    __shared__ int wsum[16];
    int tid = threadIdx.x;
    int i = blockIdx.x * 1024 + tid;
    int lane = tid & 63, wid = tid >> 6;
    int v = (i < N) ? cnt[i] : 0;
    int incl = v;
    #pragma unroll
    for (int off = 1; off < 64; off <<= 1) {
        int t = __shfl_up(incl, off);
        if (lane >= off) incl += t;
    }
    if (lane == 63) wsum[wid] = incl;
    __syncthreads();
    if (wid == 0) {
        int w = (lane < 16) ? wsum[lane] : 0;
        #pragma unroll
        for (int off = 1; off < 16; off <<= 1) {
            int t = __shfl_up(w, off);
            if (lane >= off) w += t;
        }
        if (lane < 16) wsum[lane] = w;
    }
    __syncthreads();
    int woff = (wid > 0) ? wsum[wid - 1] : 0;
    int e = woff + incl - v;
    if (i < N) excl[i] = e;
    if (tid == 1023) bsum[blockIdx.x] = woff + incl;
}

__global__ void scan2_kernel(const int* __restrict__ bsum, int* __restrict__ boff,
                             int* __restrict__ indptrN, int nb) {
    int lane = threadIdx.x;
    int v = (lane < nb) ? bsum[lane] : 0;
    int incl = v;
    #pragma unroll
    for (int off = 1; off < 64; off <<= 1) {
        int t = __shfl_up(incl, off);
        if (lane >= off) incl += t;
    }
    if (lane < nb) boff[lane] = incl - v;
    if (lane == 63) *indptrN = incl;
}

__global__ void scan3_kernel(const int* __restrict__ boff, int* __restrict__ indptr,
                             int* __restrict__ fill, int N) {
    int i = blockIdx.x * 256 + threadIdx.x;
    if (i >= N) return;
    int e = indptr[i] + boff[i >> 10];
    indptr[i] = e;
    fill[i] = e;
}

__global__ void scatter_kernel(const int* __restrict__ row, const int* __restrict__ col,
                               int* __restrict__ fill, int* __restrict__ csr,
                               int E, int N) {
    int k = blockIdx.x * 256 + threadIdx.x;
    int tot = E + N;
    if (k >= tot) return;
    int c = (k < E) ? col[k] : (k - E);
    int r = (k < E) ? row[k] : (k - E);
    int pos = atomicAdd(&fill[c], 1);
    csr[pos] = r;
}

// ---------------- fused prep: cvt x, transpose W0/W1, pack Wout ----------------

__global__ void prep_all_kernel(const float* __restrict__ x, __hip_bfloat16* __restrict__ xb,
                                long nx,
                                const float* __restrict__ W0, __hip_bfloat16* __restrict__ Wt0,
                                const float* __restrict__ W1, __hip_bfloat16* __restrict__ Wt1,
                                const float* __restrict__ Wout, __hip_bfloat16* __restrict__ WtO,
                                int nbA, int nbB, int nbC) {
    int b = blockIdx.x;
    if (b < nbA) {
        long i = ((long)b * 256 + threadIdx.x) * 4;
        if (i + 3 >= nx) {
            for (long j = i; j < nx; j++) xb[j] = __float2bfloat16(x[j]);
            return;
        }
        float4 v = *(const float4*)(x + i);
        xb[i + 0] = __float2bfloat16(v.x);
        xb[i + 1] = __float2bfloat16(v.y);
        xb[i + 2] = __float2bfloat16(v.z);
        xb[i + 3] = __float2bfloat16(v.w);
    } else if (b < nbA + nbB) {
        long i = (long)(b - nbA) * 256 + threadIdx.x;
        const int K = IN_F;
        if (i >= (long)HEADS * K * 64) return;
        int n = i & 63;
        long rest = i >> 6;
        int k = (int)(rest % K);
        int h = (int)(rest / K);
        Wt0[((long)h * 64 + n) * K + k] = __float2bfloat16(W0[i]);
    } else if (b < nbA + nbB + nbC) {
        long i = (long)(b - nbA - nbB) * 256 + threadIdx.x;
        const int K = F1;
        if (i >= (long)HEADS * K * 64) return;
        int n = i & 63;
        long rest = i >> 6;
        int k = (int)(rest % K);
        int h = (int)(rest / K);
        Wt1[((long)h * 64 + n) * K + k] = __float2bfloat16(W1[i]);
    } else {
        int i = (b - nbA - nbB - nbC) * 256 + threadIdx.x;
        if (i >= 64 * 512) return;
        int k = i & 511;
        int n = i >> 9;
        WtO[i] = __float2bfloat16(n < OUTC ? Wout[(long)k * OUTC + n] : 0.f);
    }
}

// ---------------- dense 128x128 bf16 MFMA GEMM + fused scores (R8 version) -----
// BK=32, register prefetch of iteration k+1 between the LDS-store barrier and
// the MFMA block. Epilogue fuses per-head attention scores.

__global__ __launch_bounds__(256) void gemm128(
    const __hip_bfloat16* __restrict__ A, const __hip_bfloat16* __restrict__ Bt,
    __hip_bfloat16* __restrict__ Cb, const float* __restrict__ av,
    float* __restrict__ ssrc, float* __restrict__ sdst, int M, int K) {
    constexpr int LDA = 40;
    __shared__ __hip_bfloat16 As[128 * LDA];
    __shared__ __hip_bfloat16 Bs[128 * LDA];
    int tid = threadIdx.x;
    int m0 = blockIdx.x * 128;
    int n0 = blockIdx.y * 128;
    int lane = tid & 63, wave = tid >> 6;
    int wm = (wave & 1) * 64, wn = (wave >> 1) * 64;
    int fr = lane & 15, fq = lane >> 4;
    int srow = tid >> 1, scol = (tid & 1) * 16;
    int h = blockIdx.y * 2 + (wave >> 1);     // this wave's head

    const __hip_bfloat16* Arow = A + (long)min(m0 + srow, M - 1) * K;
    const __hip_bfloat16* Brow = Bt + (long)(n0 + srow) * K;

    f32x4 acc[4][4] = {};

    float4 av0 = *(const float4*)(Arow + scol);
    float4 av1 = *(const float4*)(Arow + scol + 8);
    float4 bv0 = *(const float4*)(Brow + scol);
    float4 bv1 = *(const float4*)(Brow + scol + 8);

    for (int k0 = 0; k0 < K; k0 += 32) {
        __syncthreads();
        *(float4*)(As + srow * LDA + scol) = av0;
        *(float4*)(As + srow * LDA + scol + 8) = av1;
        *(float4*)(Bs + srow * LDA + scol) = bv0;
        *(float4*)(Bs + srow * LDA + scol + 8) = bv1;
        __syncthreads();
        int kn = (k0 + 32 < K) ? k0 + 32 : 0;
        av0 = *(const float4*)(Arow + kn + scol);
        av1 = *(const float4*)(Arow + kn + scol + 8);
        bv0 = *(const float4*)(Brow + kn + scol);
        bv1 = *(const float4*)(Brow + kn + scol + 8);
        bf16x8 af[4], bfr[4];
        #pragma unroll
        for (int mi = 0; mi < 4; mi++)
            af[mi] = *(const bf16x8*)(As + (wm + mi * 16 + fr) * LDA + fq * 8);
        #pragma unroll
        for (int ni = 0; ni < 4; ni++)
            bfr[ni] = *(const bf16x8*)(Bs + (wn + ni * 16 + fr) * LDA + fq * 8);
        #pragma unroll
        for (int mi = 0; mi < 4; mi++)
            #pragma unroll
            for (int ni = 0; ni < 4; ni++)
                acc[mi][ni] = __builtin_amdgcn_mfma_f32_16x16x32_bf16(
                    af[mi], bfr[ni], acc[mi][ni], 0, 0, 0);
    }

    #pragma unroll
    for (int mi = 0; mi < 4; mi++)
        #pragma unroll
        for (int ni = 0; ni < 4; ni++)
            #pragma unroll
            for (int rr = 0; rr < 4; rr++) {
                int m = m0 + wm + mi * 16 + fq * 4 + rr;
                int n = n0 + wn + ni * 16 + fr;
                if (m < M)
                    Cb[(long)m * F1 + n] = __float2bfloat16(acc[mi][ni][rr]);
            }

    const float* ah = av + h * 2 * HID;
    float a_src[4], a_dst[4];
    #pragma unroll
    for (int ni = 0; ni < 4; ni++) {
        a_src[ni] = ah[ni * 16 + fr];
        a_dst[ni] = ah[64 + ni * 16 + fr];
    }
    #pragma unroll
    for (int mi = 0; mi < 4; mi++)
        #pragma unroll
        for (int rr = 0; rr < 4; rr++) {
            float ps = 0.f, pd = 0.f;
            #pragma unroll
            for (int ni = 0; ni < 4; ni++) {
                ps += acc[mi][ni][rr] * a_src[ni];
                pd += acc[mi][ni][rr] * a_dst[ni];
            }
            #pragma unroll
            for (int o = 1; o < 16; o <<= 1) {
                ps += __shfl_xor(ps, o);
                pd += __shfl_xor(pd, o);
            }
            int m = m0 + wm + mi * 16 + fq * 4 + rr;
            if (fr == 0 && m < M) {
                ssrc[m * HEADS + h] = ps;
                sdst[m * HEADS + h] = pd;
            }
        }
}

// ---------------- out-layer GEMM (bf16 C [N,40]) + fused scores ----------------

__global__ __launch_bounds__(256) void gemm_out(
    const __hip_bfloat16* __restrict__ A, const __hip_bfloat16* __restrict__ Bt,
    __hip_bfloat16* __restrict__ Cb, const float* __restrict__ av,
    float* __restrict__ ssrc, float* __restrict__ sdst, int M, int K) {
    constexpr int LDA = 40;
    __shared__ __hip_bfloat16 As[128 * LDA];
    __shared__ __hip_bfloat16 Bs[64 * LDA];
    int tid = threadIdx.x;
    int m0 = blockIdx.x * 128;
    int lane = tid & 63, wave = tid >> 6;
    int wm = wave * 32;
    int arow = tid >> 2, acol = (tid & 3) * 8;
    int fr = lane & 15, fq = lane >> 4;

    const __hip_bfloat16* Apa = A + (long)min(m0 + arow, M - 1) * K + acol;
    const __hip_bfloat16* Apb = A + (long)min(m0 + 64 + arow, M - 1) * K + acol;
    const __hip_bfloat16* Bp  = Bt + (long)arow * K + acol;

    f32x4 acc[2][4] = {};

    float4 av1 = *(const float4*)(Apa);
    float4 av2 = *(const float4*)(Apb);
    float4 bv  = *(const float4*)(Bp);

    for (int k0 = 0; k0 < K; k0 += 32) {
        __syncthreads();
        *(float4*)(As + arow * LDA + acol) = av1;
        *(float4*)(As + (64 + arow) * LDA + acol) = av2;
        *(float4*)(Bs + arow * LDA + acol) = bv;
        __syncthreads();
        int kn = (k0 + 32 < K) ? k0 + 32 : 0;
        av1 = *(const float4*)(Apa + kn);
        av2 = *(const float4*)(Apb + kn);
        bv  = *(const float4*)(Bp + kn);
        bf16x8 a0 = *(const bf16x8*)(As + (wm + fr) * LDA + fq * 8);
        bf16x8 a1 = *(const bf16x8*)(As + (wm + 16 + fr) * LDA + fq * 8);
        #pragma unroll
        for (int ni = 0; ni < 4; ni++) {
            bf16x8 b = *(const bf16x8*)(Bs + (ni * 16 + fr) * LDA + fq * 8);
            acc[0][ni] = __builtin_amdgcn_mfma_f32_16x16x32_bf16(a0, b, acc[0][ni], 0, 0, 0);
            acc[1][ni] = __builtin_amdgcn_mfma_f32_16x16x32_bf16(a1, b, acc[1][ni], 0, 0, 0);
        }
    }

    #pragma unroll
    for (int mi = 0; mi < 2; mi++)
        #pragma unroll
        for (int ni = 0; ni < 4; ni++)
            #pragma unroll
            for (int rr = 0; rr < 4; rr++) {
                int m = m0 + wm + mi * 16 + fq * 4 + rr;
                int n = ni * 16 + fr;
                if (m < M && n < OUTC)
                    Cb[(long)m * OUTC + n] = __float2bfloat16(acc[mi][ni][rr]);
            }

    float a_src[4], a_dst[4];
    #pragma unroll
    for (int ni = 0; ni < 4; ni++) {
        int c = ni * 16 + fr;
        a_src[ni] = (c < OUTC) ? av[c] : 0.f;
        a_dst[ni] = (c < OUTC) ? av[OUTC + c] : 0.f;
    }
    #pragma unroll
    for (int mi = 0; mi < 2; mi++)
        #pragma unroll
        for (int rr = 0; rr < 4; rr++) {
            float ps = 0.f, pd = 0.f;
            #pragma unroll
            for (int ni = 0; ni < 4; ni++) {
                ps += acc[mi][ni][rr] * a_src[ni];
                pd += acc[mi][ni][rr] * a_dst[ni];
            }
            #pragma unroll
            for (int o = 1; o < 16; o <<= 1) {
                ps += __shfl_xor(ps, o);
                pd += __shfl_xor(pd, o);
            }
            int m = m0 + wm + mi * 16 + fq * 4 + rr;
            if (fr == 0 && m < M) {
                ssrc[m] = ps;
                sdst[m] = pd;
            }
        }
}

// ---------------- aggregation: one wave per node, ALL 8 heads ----------------

__global__ __launch_bounds__(256) void agg8_kernel(
    const __hip_bfloat16* __restrict__ Whb, const float* __restrict__ ssrc,
    const float* __restrict__ sdst, const int* __restrict__ csr,
    const int* __restrict__ indptr, __hip_bfloat16* __restrict__ H, int N) {
    int node = blockIdx.x * 4 + (threadIdx.x >> 6);
    if (node >= N) return;
    int lane = threadIdx.x & 63;
    int h = lane >> 3;
    int e8 = lane & 7;
    int base_h = lane & 56;
    int s = __builtin_amdgcn_readfirstlane(indptr[node]);
    int e = __builtin_amdgcn_readfirstlane(indptr[node + 1]);
    float sd = sdst[node * HEADS + h];
    const __hip_bfloat16* wl = Whb + lane * 8;

    float acc[8] = {};
    float m_run = -1e30f, d_run = 0.f;

    for (int jb = s; jb < e; jb += 8) {
        int cnt = min(8, e - jb);
        int src_i = 0;
        float x_i = -1e30f;
        if (e8 < cnt) {
            src_i = csr[jb + e8];
            float x = ssrc[src_i * HEADS + h] + sd;
            x_i = x > 0.f ? x : ALPHA_SLOPE * x;
        }
        float tm = x_i;
        tm = fmaxf(tm, __shfl_xor(tm, 1));
        tm = fmaxf(tm, __shfl_xor(tm, 2));
        tm = fmaxf(tm, __shfl_xor(tm, 4));
        float nm = fmaxf(m_run, tm);
        float scale = __expf(m_run - nm);
        #pragma unroll
        for (int k = 0; k < 8; k++) acc[k] *= scale;
        d_run *= scale;
        m_run = nm;
        float w_i = __expf(x_i - nm);
        float ts = w_i;
        ts += __shfl_xor(ts, 1);
        ts += __shfl_xor(ts, 2);
        ts += __shfl_xor(ts, 4);
        d_run += ts;

        if (cnt == 8) {
            uint4 d[8];
            #pragma unroll
            for (int u = 0; u < 8; u++) {
                int su = __shfl(src_i, u);
                d[u] = *(const uint4*)(wl + (long)su * F1);
            }
            #pragma unroll
            for (int u = 0; u < 8; u++) {
                float wj = __shfl(w_i, base_h + u);
                acc[0] += wj * __uint_as_float(d[u].x << 16);
                acc[1] += wj * __uint_as_float(d[u].x & 0xffff0000u);
                acc[2] += wj * __uint_as_float(d[u].y << 16);
                acc[3] += wj * __uint_as_float(d[u].y & 0xffff0000u);
                acc[4] += wj * __uint_as_float(d[u].z << 16);
                acc[5] += wj * __uint_as_float(d[u].z & 0xffff0000u);
                acc[6] += wj * __uint_as_float(d[u].w << 16);
                acc[7] += wj * __uint_as_float(d[u].w & 0xffff0000u);
            }
        } else {
            for (int u = 0; u < cnt; u++) {
                float wj = __shfl(w_i, base_h + u);
                int   su = __shfl(src_i, u);
                uint4 d = *(const uint4*)(wl + (long)su * F1);
                acc[0] += wj * __uint_as_float(d.x << 16);
                acc[1] += wj * __uint_as_float(d.x & 0xffff0000u);
                acc[2] += wj * __uint_as_float(d.y << 16);
                acc[3] += wj * __uint_as_float(d.y & 0xffff0000u);
                acc[4] += wj * __uint_as_float(d.z << 16);
                acc[5] += wj * __uint_as_float(d.z & 0xffff0000u);
                acc[6] += wj * __uint_as_float(d.w << 16);
                acc[7] += wj * __uint_as_float(d.w & 0xffff0000u);
            }
        }
    }

    float inv = 1.f / d_run;
    unsigned short us[8];
    #pragma unroll
    for (int k = 0; k < 8; k++) {
        float v = acc[k] * inv;
        v = v > 0.f ? v : (__expf(v) - 1.f);
        __hip_bfloat16 b = __float2bfloat16(v);
        __builtin_memcpy(&us[k], &b, 2);
    }
    uint4 ov;
    __builtin_memcpy(&ov, us, 16);
    *(uint4*)(H + (long)node * F1 + lane * 8) = ov;
}

// ---------------- out aggregation (bf16 gather, batched) + log_softmax --------

__global__ __launch_bounds__(256) void aggout_kernel(
    const __hip_bfloat16* __restrict__ Whb, const float* __restrict__ ssrc,
    const float* __restrict__ sdst, const int* __restrict__ csr,
    const int* __restrict__ indptr, float* __restrict__ out, int N) {
    int node = blockIdx.x * 4 + (threadIdx.x >> 6);
    if (node >= N) return;
    int lane = threadIdx.x & 63;
    int s = __builtin_amdgcn_readfirstlane(indptr[node]);
    int e = __builtin_amdgcn_readfirstlane(indptr[node + 1]);
    float sd = sdst[node];
    int lc = min(lane, OUTC - 1);
    const __hip_bfloat16* whb = Whb + lc;

    float m_run = -1e30f, d_run = 0.f, acc0 = 0.f, acc1 = 0.f;
    for (int t = s; t < e; t += 64) {
        int cnt = min(64, e - t);
        int src_i = node;
        float x_i = -1e30f;
        if (lane < cnt) {
            src_i = csr[t + lane];
            float x = ssrc[src_i] + sd;
            x_i = x > 0.f ? x : ALPHA_SLOPE * x;
        }
        float tm = x_i;
        #pragma unroll
        for (int o = 32; o; o >>= 1) tm = fmaxf(tm, __shfl_xor(tm, o));
        float nm = fmaxf(m_run, tm);
        float scale = __expf(m_run - nm);
        acc0 *= scale; acc1 *= scale; d_run *= scale;
        m_run = nm;
        float w_i = __expf(x_i - nm);
        float ts = w_i;
        #pragma unroll
        for (int o = 32; o; o >>= 1) ts += __shfl_xor(ts, o);
        d_run += ts;
        int cnt8 = (cnt + 7) & ~7;         // pad lanes: w=0, src=node (safe)
        for (int j = 0; j < cnt8; j += 8) {
            float dv[8], wj[8];
            #pragma unroll
            for (int u = 0; u < 8; u++) {
                int sj = __shfl(src_i, j + u);
                wj[u] = __shfl(w_i, j + u);
                dv[u] = __bfloat162float(whb[(long)sj * OUTC]);
            }
            #pragma unroll
            for (int u = 0; u < 8; u += 2) {
                acc0 += wj[u] * dv[u];
                acc1 += wj[u + 1] * dv[u + 1];
            }
        }
    }
    float g = (acc0 + acc1) / d_run;
    float v = g > 0.f ? g : (__expf(g) - 1.f);
    float vm = (lane < OUTC) ? v : -1e30f;
    #pragma unroll
    for (int o = 32; o; o >>= 1) vm = fmaxf(vm, __shfl_xor(vm, o));
    float ex = (lane < OUTC) ? __expf(v - vm) : 0.f;
    #pragma unroll
    for (int o = 32; o; o >>= 1) ex += __shfl_xor(ex, o);
    if (lane < OUTC) out[(long)node * OUTC + lane] = v - vm - logf(ex);
}

// ---------------- launch ----------------

extern "C" void kernel_launch(void* const* d_in, const int* in_sizes, int n_in,
                              void* d_out, int out_size, void* d_ws, size_t ws_size,
                              hipStream_t stream) {
    const float* x    = (const float*)d_in[0];
    const int*   ei   = (const int*)d_in[1];
    const float* W0   = (const float*)d_in[2];
    const float* a0   = (const float*)d_in[3];
    const float* W1   = (const float*)d_in[4];
    const float* a1   = (const float*)d_in[5];
    const float* Wout = (const float*)d_in[6];
    const float* aout = (const float*)d_in[7];
    float* out = (float*)d_out;

    const int N = in_sizes[0] / IN_F;
    const int E = in_sizes[1] / 2;
    const int Etot = E + N;
    const int* erow = ei;
    const int* ecol = ei + E;

    char* p = (char*)d_ws;
    auto carve = [&](size_t bytes) {
        void* r = (void*)p;
        p += (bytes + 255) & ~(size_t)255;
        return r;
    };
    __hip_bfloat16*  Whb  = (__hip_bfloat16*)carve((size_t)N * F1 * 2);
    __hip_bfloat16*  Hb   = (__hip_bfloat16*)carve((size_t)N * F1 * 2);
    __hip_bfloat16*  WhOb = (__hip_bfloat16*)carve((size_t)N * OUTC * 2);
    __hip_bfloat16*  xb   = (__hip_bfloat16*)carve((size_t)N * IN_F * 2);
    __hip_bfloat16*  Wt0  = (__hip_bfloat16*)carve((size_t)F1 * IN_F * 2);
    __hip_bfloat16*  Wt1  = (__hip_bfloat16*)carve((size_t)F1 * F1 * 2);
    __hip_bfloat16*  WtO  = (__hip_bfloat16*)carve((size_t)64 * F1 * 2);
    float*  ssrc   = (float*)carve((size_t)N * HEADS * 4);
    float*  sdst   = (float*)carve((size_t)N * HEADS * 4);
    int*    cnt    = (int*)carve((size_t)N * 4);
    int*    indptr = (int*)carve((size_t)(N + 1) * 4);
    int*    fill   = (int*)carve((size_t)N * 4);
    int*    csr    = (int*)carve((size_t)Etot * 4);
    int*    bsum   = (int*)carve(64 * 4);
    int*    boff   = (int*)carve(64 * 4);

    // CSR build
    hipMemsetAsync(cnt, 0, (size_t)N * 4, stream);
    int eb = (Etot + 255) / 256;
    int nb = (N + 1023) / 1024;   // <=64 required by scan2
    hist_kernel<<<eb, 256, 0, stream>>>(ecol, cnt, E, N);
    scan1_kernel<<<nb, 1024, 0, stream>>>(cnt, indptr, bsum, N);
    scan2_kernel<<<1, 64, 0, stream>>>(bsum, boff, indptr + N, nb);
    scan3_kernel<<<(N + 255) / 256, 256, 0, stream>>>(boff, indptr, fill, N);
    scatter_kernel<<<eb, 256, 0, stream>>>(erow, ecol, fill, csr, E, N);

    // fused prep
    long nx = (long)N * IN_F;
    int nbA = (int)((nx / 4 + 255) / 256);
    int nbB = (HEADS * IN_F * 64 + 255) / 256;
    int nbC = (HEADS * F1 * 64 + 255) / 256;
    int nbD = (64 * 512 + 255) / 256;
    prep_all_kernel<<<nbA + nbB + nbC + nbD, 256, 0, stream>>>(
        x, xb, nx, W0, Wt0, W1, Wt1, Wout, WtO, nbA, nbB, nbC);

    int mt128 = (N + 127) / 128;
    int wb1 = (N + 3) / 4;

    // Layer 0
    gemm128<<<dim3(mt128, 4), 256, 0, stream>>>(xb, Wt0, Whb, a0, ssrc, sdst, N, IN_F);
    agg8_kernel<<<wb1, 256, 0, stream>>>(Whb, ssrc, sdst, csr, indptr, Hb, N);

    // Layer 1
    gemm128<<<dim3(mt128, 4), 256, 0, stream>>>(Hb, Wt1, Whb, a1, ssrc, sdst, N, F1);
    agg8_kernel<<<wb1, 256, 0, stream>>>(Whb, ssrc, sdst, csr, indptr, Hb, N);

    // Out layer
    gemm_out<<<dim3(mt128, 1), 256, 0, stream>>>(Hb, WtO, WhOb, aout, ssrc, sdst, N, F1);
    aggout_kernel<<<wb1, 256, 0, stream>>>(WhOb, ssrc, sdst, csr, indptr, out, N);
}